// Round 1
// baseline (297.892 us; speedup 1.0000x reference)
//
#include <hip/hip_runtime.h>

#define FD 128      // feature dim (both layers)
#define BSH 7       // log2(nodes per bucket) = 128 nodes/bucket
#define CH 2048     // edges per partition block
#define CHT 8       // edges per thread (CH / 256)
#define KMAX 512    // max buckets
#define SCAP 8192   // build_kernel LDS edge stage
#define NCH 8       // src chunks (chunk = src >> CSH); requires N <= 57344
#define CSH 13      // 8192 nodes/chunk -> 2 MB of h' per chunk (fits 4 MB per-XCD L2)
#define NPW 7       // nodes per wave in agg (grid = 1786 = 7 blocks/CU co-resident)
// packed pair: (local_dst << 17) | src   -- requires N <= 131072

typedef __attribute__((ext_vector_type(8))) short bf16x8;
typedef __attribute__((ext_vector_type(4))) float f32x4;

__device__ inline unsigned bfr(float f) {   // fp32 -> bf16 bits, round-nearest-even
    unsigned u = __float_as_uint(f);
    return (u + 0x7FFF + ((u >> 16) & 1)) >> 16;
}
__device__ inline float uplo(unsigned p) { return __uint_as_float(p << 16); }
__device__ inline float uphi(unsigned p) { return __uint_as_float(p & 0xFFFF0000u); }

// ---------------- CSR build ----------------
// R13 scheme: R12 partition (chunk multi-split, 1.0x write density) unchanged.
// build_kernel now bins per (row, src-chunk): col within each row is ordered by
// src chunk and rpc[p][v] gives per-chunk row boundaries, enabling the agg
// kernel's L2-resident chunk sweep. lstartG is transposed (tr_kernel) so
// build's fragment-descriptor reads are coalesced.

__global__ __launch_bounds__(256) void partition_kernel(
        const int* __restrict__ src, const int* __restrict__ dst,
        int* __restrict__ lstartG, int* __restrict__ total,
        int* __restrict__ pairs, int E, int K) {
    __shared__ int lcnt[KMAX];     // counts, then scatter cursor
    __shared__ int lstart[KMAX];   // local exclusive prefix
    __shared__ int sm[256];
    __shared__ int staged[CH];
    int t = threadIdx.x;
    int base = blockIdx.x * CH;
    int n = min(CH, E - base);

    lcnt[t] = 0; lcnt[t + 256] = 0;
    __syncthreads();

    int pk[CHT]; int bn[CHT];
    #pragma unroll
    for (int j = 0; j < CHT; ++j) {
        int i = t + j * 256;
        bn[j] = -1;
        if (i < n) {
            int d = dst[base + i];
            int s = src[base + i];
            bn[j] = d >> BSH;
            pk[j] = ((d & ((1 << BSH) - 1)) << 17) | s;
            atomicAdd(&lcnt[bn[j]], 1);
        }
    }
    __syncthreads();

    // exclusive scan of 512 bins, 2 consecutive bins per thread
    int c0 = lcnt[2 * t], c1 = lcnt[2 * t + 1];
    int s2 = c0 + c1;
    sm[t] = s2;
    __syncthreads();
    for (int off = 1; off < 256; off <<= 1) {
        int add = (t >= off) ? sm[t - off] : 0;
        __syncthreads();
        sm[t] += add;
        __syncthreads();
    }
    int ex = sm[t] - s2;
    lstart[2 * t] = ex;     lstart[2 * t + 1] = ex + c0;
    lcnt[2 * t]   = ex;     lcnt[2 * t + 1]   = ex + c0;   // cursor
    __syncthreads();

    // scatter chunk into staged[], sorted by bucket
    #pragma unroll
    for (int j = 0; j < CHT; ++j) {
        if (bn[j] >= 0) {
            int pos = atomicAdd(&lcnt[bn[j]], 1);
            staged[pos] = pk[j];
        }
    }
    __syncthreads();

    // sequential coalesced copy-out: this block owns pairs[base .. base+n)
    for (int i = t; i < n; i += 256)
        pairs[base + i] = staged[i];

    // per-block bucket boundaries + bucket totals
    size_t lrow = (size_t)blockIdx.x * (K + 1);
    for (int b = t; b < K; b += 256) {
        lstartG[lrow + b] = lstart[b];
        int c = lcnt[b] - lstart[b];
        if (c) atomicAdd(&total[b], c);
    }
    if (t == 0) lstartG[lrow + K] = n;
}

// exclusive scan of K bucket totals -> bbase; also rp[N]=E
__global__ __launch_bounds__(512) void totscan_kernel(
        const int* __restrict__ total, int* __restrict__ bbase,
        int* __restrict__ rp, int K, int E, int N) {
    __shared__ int sm[512];
    int t = threadIdx.x;
    int v = (t < K) ? total[t] : 0;
    sm[t] = v;
    __syncthreads();
    for (int off = 1; off < 512; off <<= 1) {
        int add = (t >= off) ? sm[t - off] : 0;
        __syncthreads();
        sm[t] += add;
        __syncthreads();
    }
    if (t < K) bbase[t] = sm[t] - v;
    if (t == 0) { bbase[K] = E; rp[N] = E; }
}

// transpose A[R][C] -> B[C][R]  (lstartG [PB][K+1] -> lstartT [K+1][PB])
// so build's per-fragment descriptor reads are coalesced instead of
// stride-(K+1)*4B scattered.
__global__ __launch_bounds__(256) void tr_kernel(
        const int* __restrict__ A, int* __restrict__ B, int R, int C) {
    __shared__ int tile[32][33];
    int c0 = blockIdx.x * 32, r0 = blockIdx.y * 32;
    int tx = threadIdx.x, ty = threadIdx.y;   // block (32, 8)
    for (int i = ty; i < 32; i += 8) {
        int r = r0 + i, c = c0 + tx;
        if (r < R && c < C) tile[i][tx] = A[(size_t)r * C + c];
    }
    __syncthreads();
    for (int i = ty; i < 32; i += 8) {
        int c = c0 + i, r = r0 + tx;
        if (c < C && r < R) B[(size_t)c * R + r] = tile[tx][i];
    }
}

// Per-bucket: gather fragments into LDS, bin per (row, src-chunk) (1024 bins),
// scan, write rp/dis/rpc, scatter col in (row, chunk) order.
__global__ __launch_bounds__(256) void build_kernel(
        const int* __restrict__ pairs, const int* __restrict__ lstartT,
        const int* __restrict__ bbase, int* __restrict__ rp,
        int* __restrict__ rpc, float* __restrict__ dis,
        int* __restrict__ col, int N, int PB, int K) {
    __shared__ int staged[SCAP];
    __shared__ int lcnt[128 * NCH];   // counts, then absolute scatter cursor
    __shared__ int pref[128 * NCH];   // bucket-local exclusive prefix
    __shared__ int sm[256];
    int b = blockIdx.x;
    int t = threadIdx.x;
    int nbase = b << BSH;
    int nn = min(1 << BSH, N - nbase);
    int beg = bbase[b];
    int cnt = bbase[b + 1] - beg;

    // fragment descriptors (coalesced reads from transposed lstart)
    int fp[4], fl0[4], flen[4];
    int nf = 0, mysum = 0;
    for (int p = t; p < PB; p += 256) {
        int l0 = lstartT[(size_t)b * PB + p];
        int l1 = lstartT[(size_t)(b + 1) * PB + p];
        fp[nf] = p; fl0[nf] = l0; flen[nf] = l1 - l0;
        mysum += l1 - l0;
        ++nf;
    }
    // exclusive scan of per-thread sums -> dest offsets in staged
    sm[t] = mysum;
    __syncthreads();
    for (int off = 1; off < 256; off <<= 1) {
        int add = (t >= off) ? sm[t - off] : 0;
        __syncthreads();
        sm[t] += add;
        __syncthreads();
    }
    int o = sm[t] - mysum;

    lcnt[t] = 0; lcnt[t + 256] = 0; lcnt[t + 512] = 0; lcnt[t + 768] = 0;

    if (cnt <= SCAP) {   // fast path (always, for Poisson buckets)
        for (int f = 0; f < nf; ++f) {
            int gbase = fp[f] * CH + fl0[f];
            for (int i = 0; i < flen[f]; ++i) staged[o + i] = pairs[gbase + i];
            o += flen[f];
        }
        __syncthreads();
        for (int i = t; i < cnt; i += 256) {
            int p = staged[i];
            atomicAdd(&lcnt[((p >> 17) << 3) | ((p & 0x1FFFF) >> CSH)], 1);
        }
    } else {             // overflow fallback: count directly from global
        __syncthreads();
        for (int f = 0; f < nf; ++f) {
            int gbase = fp[f] * CH + fl0[f];
            for (int i = 0; i < flen[f]; ++i) {
                int p = pairs[gbase + i];
                atomicAdd(&lcnt[((p >> 17) << 3) | ((p & 0x1FFFF) >> CSH)], 1);
            }
        }
    }
    __syncthreads();

    // exclusive scan of 1024 bins, 4 consecutive per thread
    int b0 = 4 * t;
    int c0 = lcnt[b0], c1 = lcnt[b0 + 1], c2 = lcnt[b0 + 2], c3 = lcnt[b0 + 3];
    int s4 = c0 + c1 + c2 + c3;
    sm[t] = s4;
    __syncthreads();
    for (int off = 1; off < 256; off <<= 1) {
        int add = (t >= off) ? sm[t - off] : 0;
        __syncthreads();
        sm[t] += add;
        __syncthreads();
    }
    int ex = sm[t] - s4;
    pref[b0] = ex; pref[b0 + 1] = ex + c0;
    pref[b0 + 2] = ex + c0 + c1; pref[b0 + 3] = ex + c0 + c1 + c2;
    __syncthreads();

    // rp / dis (row totals) + rpc (per-chunk row starts, planes 0..7;
    // plane 7 == row end since chunk 7 is empty for N <= 57344)
    if (t < 128 && t < nn) {
        int rs = pref[t << 3];
        int re = (t < 127) ? pref[(t + 1) << 3] : cnt;
        rp[nbase + t] = beg + rs;
        dis[nbase + t] = rsqrtf((float)(re - rs + 1));  // deg incl. self-loop
    }
    #pragma unroll
    for (int j = 0; j < 4; ++j) {
        int bin = b0 + j;
        int row = bin >> 3, p = bin & (NCH - 1);
        if (row < nn) rpc[(size_t)p * N + nbase + row] = beg + pref[bin];
    }
    __syncthreads();
    lcnt[b0]     = beg + pref[b0];
    lcnt[b0 + 1] = beg + pref[b0 + 1];
    lcnt[b0 + 2] = beg + pref[b0 + 2];
    lcnt[b0 + 3] = beg + pref[b0 + 3];
    __syncthreads();

    if (cnt <= SCAP) {
        for (int i = t; i < cnt; i += 256) {
            int p = staged[i];
            int key = ((p >> 17) << 3) | ((p & 0x1FFFF) >> CSH);
            int pos = atomicAdd(&lcnt[key], 1);
            col[pos] = p & 0x1FFFF;
        }
    } else {
        for (int f = 0; f < nf; ++f) {
            int gbase = fp[f] * CH + fl0[f];
            for (int i = 0; i < flen[f]; ++i) {
                int p = pairs[gbase + i];
                int key = ((p >> 17) << 3) | ((p & 0x1FFFF) >> CSH);
                int pos = atomicAdd(&lcnt[key], 1);
                col[pos] = p & 0x1FFFF;
            }
        }
    }
}

// ---------------- precision prep ----------------

__global__ void wt_kernel(const float* __restrict__ W1, unsigned short* __restrict__ W1T,
                          const float* __restrict__ W2, unsigned short* __restrict__ W2T) {
    int k = blockIdx.x & (FD - 1);
    int n = threadIdx.x;
    if (blockIdx.x < FD) W1T[n * FD + k] = (unsigned short)bfr(W1[k * FD + n]);
    else                 W2T[n * FD + k] = (unsigned short)bfr(W2[k * FD + n]);
}

// ---------------- MFMA bf16 GEMM: C = bf16( dis[row] * (A @ W) ) ----------------

#define APAD 8
#define ASTR (FD + APAD)

template <bool A32>
__device__ void gemm_body(const void* __restrict__ Ap,
                          const unsigned short* __restrict__ WT,
                          const float* __restrict__ dis,
                          unsigned short* __restrict__ C, int M) {
    __shared__ unsigned short As[128 * ASTR];
    __shared__ unsigned short Bs[128 * ASTR];
    int tid = threadIdx.x;
    int lane = tid & 63;
    int wave = tid >> 6;
    int quad = lane >> 4;
    int l16 = lane & 15;
    int rowBase = blockIdx.x * 128;

    #pragma unroll
    for (int p = 0; p < 8; ++p) {
        int r = p * 16 + (tid >> 4);
        int cq = (tid & 15) * 8;
        int gr = rowBase + r;
        uint4 v = make_uint4(0u, 0u, 0u, 0u);
        if (A32) {
            if (gr < M) {
                const float* a = (const float*)Ap + (size_t)gr * FD + cq;
                float4 f0 = *(const float4*)a;
                float4 f1 = *(const float4*)(a + 4);
                v.x = bfr(f0.x) | (bfr(f0.y) << 16);
                v.y = bfr(f0.z) | (bfr(f0.w) << 16);
                v.z = bfr(f1.x) | (bfr(f1.y) << 16);
                v.w = bfr(f1.z) | (bfr(f1.w) << 16);
            }
        } else {
            if (gr < M) v = *(const uint4*)((const unsigned short*)Ap + (size_t)gr * FD + cq);
        }
        *(uint4*)&As[r * ASTR + cq] = v;
        *(uint4*)&Bs[r * ASTR + cq] = *(const uint4*)&WT[(size_t)r * FD + cq];
    }
    __syncthreads();

    int m0 = wave * 32;
    f32x4 acc[2][8] = {};
    #pragma unroll
    for (int kt = 0; kt < 4; ++kt) {
        int ko = kt * 32 + quad * 8;
        bf16x8 a0 = *(bf16x8*)&As[(m0 + l16) * ASTR + ko];
        bf16x8 a1 = *(bf16x8*)&As[(m0 + 16 + l16) * ASTR + ko];
        #pragma unroll
        for (int n = 0; n < 8; ++n) {
            bf16x8 b = *(bf16x8*)&Bs[(n * 16 + l16) * ASTR + ko];
            acc[0][n] = __builtin_amdgcn_mfma_f32_16x16x32_bf16(a0, b, acc[0][n], 0, 0, 0);
            acc[1][n] = __builtin_amdgcn_mfma_f32_16x16x32_bf16(a1, b, acc[1][n], 0, 0, 0);
        }
    }

    #pragma unroll
    for (int ms = 0; ms < 2; ++ms) {
        #pragma unroll
        for (int r = 0; r < 4; ++r) {
            int grow = rowBase + m0 + ms * 16 + quad * 4 + r;
            if (grow < M) {
                float dv = dis[grow];
                #pragma unroll
                for (int n = 0; n < 8; ++n) {
                    C[(size_t)grow * FD + n * 16 + l16] =
                        (unsigned short)bfr(dv * acc[ms][n][r]);
                }
            }
        }
    }
}

__global__ __launch_bounds__(256) void gemm_mfma_f32(
        const float* __restrict__ A, const unsigned short* __restrict__ WT,
        const float* __restrict__ dis, unsigned short* __restrict__ C, int M) {
    gemm_body<true>(A, WT, dis, C, M);
}

__global__ __launch_bounds__(256) void gemm_mfma_bf16(
        const unsigned short* __restrict__ A, const unsigned short* __restrict__ WT,
        const float* __restrict__ dis, unsigned short* __restrict__ C, int M) {
    gemm_body<false>(A, WT, dis, C, M);
}

// ---------------- CSR aggregation + bias + ReLU ----------------
// R13: src-chunk sweep. Each wave owns NPW=7 nodes (acc in registers) and all
// waves iterate src chunks in the outer loop. The grid (1786 blocks, 7/CU via
// __launch_bounds__(256,7)) is fully co-resident, so at any instant the live
// h' gather window is ~1 chunk = 2 MB per XCD -> L2-resident. col is
// chunk-ordered per row; rpc[p][v] gives the chunk boundaries.

__global__ __launch_bounds__(256, 7) void agg_kernel(
        const unsigned* __restrict__ h, const float* __restrict__ dis,
        const int* __restrict__ rpc, const int* __restrict__ col,
        const float2* __restrict__ bias, void* __restrict__ out, int N, int obf) {
    int wid = __builtin_amdgcn_readfirstlane(blockIdx.x * 4 + threadIdx.y);
    int t = threadIdx.x;                       // 0..63, feature pair
    int v0 = wid * NPW;
    if (v0 >= N) return;
    int nv = min(NPW, N - v0);

    float2 acc[NPW];
    #pragma unroll
    for (int s = 0; s < NPW; ++s) acc[s] = make_float2(0.0f, 0.0f);

    for (int p = 0; p < NCH - 1; ++p) {        // chunks 0..6 (7 empty, N<=57344)
        int st[NPW], en[NPW];
        #pragma unroll
        for (int s = 0; s < NPW; ++s) {
            if (s < nv) {
                st[s] = rpc[(size_t)p * N + v0 + s];
                en[s] = rpc[(size_t)(p + 1) * N + v0 + s];
            } else { st[s] = 0; en[s] = 0; }
        }
        #pragma unroll
        for (int s = 0; s < NPW; ++s) {
            int e = st[s], end = en[s];
            for (; e + 4 <= end; e += 4) {
                int u0 = col[e], u1 = col[e + 1], u2 = col[e + 2], u3 = col[e + 3];
                unsigned q0 = h[(size_t)u0 * 64 + t];
                unsigned q1 = h[(size_t)u1 * 64 + t];
                unsigned q2 = h[(size_t)u2 * 64 + t];
                unsigned q3 = h[(size_t)u3 * 64 + t];
                acc[s].x += uplo(q0); acc[s].y += uphi(q0);
                acc[s].x += uplo(q1); acc[s].y += uphi(q1);
                acc[s].x += uplo(q2); acc[s].y += uphi(q2);
                acc[s].x += uplo(q3); acc[s].y += uphi(q3);
            }
            for (; e < end; ++e) {
                unsigned q = h[(size_t)col[e] * 64 + t];
                acc[s].x += uplo(q); acc[s].y += uphi(q);
            }
        }
    }

    float2 bb = bias[t];
    #pragma unroll
    for (int s = 0; s < NPW; ++s) {
        if (s < nv) {
            int v = v0 + s;
            float dv = dis[v];
            size_t vb = (size_t)v * 64 + t;
            unsigned hp = h[vb];               // self term h'[v]
            float rx = fmaxf(fmaf(dv, acc[s].x + uplo(hp), bb.x), 0.0f);
            float ry = fmaxf(fmaf(dv, acc[s].y + uphi(hp), bb.y), 0.0f);
            if (obf) ((unsigned*)out)[vb] = bfr(rx) | (bfr(ry) << 16);
            else     ((float2*)out)[vb] = make_float2(rx, ry);
        }
    }
}

// ---------------- launch ----------------

extern "C" void kernel_launch(void* const* d_in, const int* in_sizes, int n_in,
                              void* d_out, int out_size, void* d_ws, size_t ws_size,
                              hipStream_t stream) {
    const float* x  = (const float*)d_in[0];
    const int*   ei = (const int*)d_in[1];   // [2, E] int32
    const float* W1 = (const float*)d_in[2];
    const float* b1 = (const float*)d_in[3];
    const float* W2 = (const float*)d_in[4];
    const float* b2 = (const float*)d_in[5];

    int N = in_sizes[0] / FD;
    int E = in_sizes[1] / 2;
    const int* src = ei;
    const int* dst = ei + E;
    int K = (N + (1 << BSH) - 1) >> BSH;     // buckets (<= 512 assumed)
    int PB = (E + CH - 1) / CH;              // partition blocks

    char* base = (char*)d_ws;
    size_t off = 0;
    auto align256 = [](size_t v) { return (v + 255) & ~(size_t)255; };
    int*            rp    = (int*)(base + off);            off += align256((size_t)(N + 1) * 4);
    float*          dis   = (float*)(base + off);          off += align256((size_t)N * 4);
    int*            total = (int*)(base + off);            off += align256(512 * 4);
    int*            bbase = (int*)(base + off);            off += align256(513 * 4);
    unsigned short* w1t   = (unsigned short*)(base + off); off += align256((size_t)FD * FD * 2);
    unsigned short* w2t   = (unsigned short*)(base + off); off += align256((size_t)FD * FD * 2);
    int*            col   = (int*)(base + off);            off += align256((size_t)E * 4);
    unsigned short* hbuf  = (unsigned short*)(base + off); off += align256((size_t)N * FD * 2);
    unsigned short* z1    = (unsigned short*)(base + off); off += align256((size_t)N * FD * 2);
    int*            pairs = (int*)(base + off);            off += align256((size_t)E * 4);
    int*            rpc   = (int*)(base + off);            off += align256((size_t)NCH * N * 4);
    int*            lstartG = (int*)hbuf;   // overlay: dead before gemm1 writes hbuf
    int*            lstartT = (int*)z1;     // overlay: dead before agg1 writes z1
    (void)ws_size; (void)n_in; (void)out_size;

    (void)hipMemsetAsync(total, 0, 512 * 4, stream);
    partition_kernel<<<PB, 256, 0, stream>>>(src, dst, lstartG, total, pairs, E, K);
    totscan_kernel  <<<1, 512, 0, stream>>>(total, bbase, rp, K, E, N);
    dim3 trb(32, 8);
    dim3 trg((K + 1 + 31) / 32, (PB + 31) / 32);
    tr_kernel       <<<trg, trb, 0, stream>>>(lstartG, lstartT, PB, K + 1);
    build_kernel    <<<K, 256, 0, stream>>>(pairs, lstartT, bbase, rp, rpc, dis, col, N, PB, K);

    wt_kernel<<<2 * FD, FD, 0, stream>>>(W1, w1t, W2, w2t);

    dim3 aggBlk(64, 4);
    int aggGrid = (N + 4 * NPW - 1) / (4 * NPW);
    int gemmGrid = (N + 127) / 128;

    gemm_mfma_f32 <<<gemmGrid, 256, 0, stream>>>(x, w1t, dis, hbuf, N);
    agg_kernel<<<aggGrid, aggBlk, 0, stream>>>((const unsigned*)hbuf, dis, rpc, col,
                                               (const float2*)b1, z1, N, 1);
    gemm_mfma_bf16<<<gemmGrid, 256, 0, stream>>>(z1, w2t, dis, hbuf, N);
    agg_kernel<<<aggGrid, aggBlk, 0, stream>>>((const unsigned*)hbuf, dis, rpc, col,
                                               (const float2*)b2, d_out, N, 0);
}